// Round 9
// baseline (288.876 us; speedup 1.0000x reference)
//
#include <hip/hip_runtime.h>

#define N_NODES 50000
#define N_EDGES 1600000
#define F 32
#define BSH 6                               // 64 nodes per bucket
#define BSIZE (1 << BSH)
#define NB ((N_NODES + BSIZE - 1) >> BSH)   // 782 buckets
#define CHUNK 2048                          // edges per coarse block -> 782 blocks
#define NCHUNK ((N_EDGES + CHUNK - 1) / CHUNK)
#define WCAP 2560                           // bucket cap: mean 2046, sigma 45 -> 11 sigma

typedef float f4 __attribute__((ext_vector_type(4)));
typedef _Float16 h4 __attribute__((ext_vector_type(4)));

__device__ __forceinline__ f4 nt_load4(const float* p) {
    return __builtin_nontemporal_load((const f4*)p);
}
__device__ __forceinline__ int nt_loadi(const int* p) {
    return __builtin_nontemporal_load(p);
}

// ---------- coarse bucket histogram (LDS-privatized) ----------
__global__ __launch_bounds__(256)
void k_bhist(const int* __restrict__ dst, int* __restrict__ bhist) {
    __shared__ int lh[NB];
    for (int i = threadIdx.x; i < NB; i += 256) lh[i] = 0;
    __syncthreads();
    for (int e = blockIdx.x * blockDim.x + threadIdx.x; e < N_EDGES;
         e += gridDim.x * blockDim.x)
        atomicAdd(&lh[dst[e] >> BSH], 1);
    __syncthreads();
    for (int i = threadIdx.x; i < NB; i += 256)
        if (lh[i]) atomicAdd(&bhist[i], lh[i]);
}

// ---------- scan NB bucket counts -> offsets + fill cursors ----------
__global__ __launch_bounds__(1024)
void k_bscan(const int* __restrict__ bhist,
             int* __restrict__ bucket_off,
             int* __restrict__ cursor) {
    __shared__ int s[1024];
    int t = threadIdx.x;
    int v = (t < NB) ? bhist[t] : 0;
    s[t] = v;
    __syncthreads();
    for (int off = 1; off < 1024; off <<= 1) {
        int u = (t >= off) ? s[t - off] : 0;
        __syncthreads();
        s[t] += u;
        __syncthreads();
    }
    if (t < NB) {
        int ex = s[t] - v;
        bucket_off[t] = ex;
        cursor[t] = ex;
    }
    if (t == NB - 1) bucket_off[NB] = s[t];
}

// ---------- phase A: bin edges into bucket runs, CARRYING f16 input rows ----------
// inputs read coalesced here (the only full read of the 205MB array);
// each scattered row write = exactly one full 64B line.
__global__ __launch_bounds__(256)
void k_coarse_rows(const int* __restrict__ dst,
                   const int* __restrict__ src,
                   const float* __restrict__ inputs,
                   int* __restrict__ cursor,
                   int* __restrict__ coarseE,
                   _Float16* __restrict__ coarseR) {
    __shared__ int lh[NB];
    __shared__ int gb[NB];
    __shared__ unsigned int ds[CHUNK];   // d<<16 | src, staged coalesced
    int lo = blockIdx.x * CHUNK;
    int hi = min(lo + CHUNK, N_EDGES);

    for (int i = threadIdx.x; i < NB; i += 256) lh[i] = 0;
    __syncthreads();
    for (int e = lo + threadIdx.x; e < hi; e += 256) {
        int d = dst[e];
        ds[e - lo] = ((unsigned)d << 16) | (unsigned)src[e];
        atomicAdd(&lh[d >> BSH], 1);
    }
    __syncthreads();
    for (int i = threadIdx.x; i < NB; i += 256) {
        gb[i] = atomicAdd(&cursor[i], lh[i]);
        lh[i] = 0;                  // reuse as rank counter
    }
    __syncthreads();

    // wave-cooperative: 8 edges per wave-iter, lane = eslot*8 + q
    int lane  = threadIdx.x & 63;
    int wv    = threadIdx.x >> 6;        // 4 waves
    int eslot = lane >> 3;
    int q     = lane & 7;
    for (int base = lo + wv * 8; base < hi; base += 32) {
        int e = base + eslot;
        bool valid = e < hi;
        int p = 0;
        if (valid && q == 0) {
            unsigned v = ds[e - lo];
            int d = (int)(v >> 16);
            int bk = d >> BSH;
            int r = atomicAdd(&lh[bk], 1);
            p = gb[bk] + r;
            coarseE[p] = ((d & (BSIZE - 1)) << 16) | (int)(v & 0xFFFFu);
        }
        p = __shfl(p, eslot * 8);
        if (valid) {
            f4 x = nt_load4(&inputs[(size_t)e * F + q * 4]);
            *reinterpret_cast<h4*>(&coarseR[((size_t)p << 5) + q * 4]) =
                __builtin_convertvector(x, h4);
        }
    }
}

// ---------- phase B fused: exact sort (in LDS) + node_mean reduce ----------
// One block per bucket. perm stays in LDS; rows read from the L3-resident
// bucket window; emits row_off + src_sorted for the h stage.
__global__ __launch_bounds__(512)
void k_bucket_mean(const int* __restrict__ coarseE,
                   const int* __restrict__ bucket_off,
                   const _Float16* __restrict__ coarseR,
                   int* __restrict__ row_off,
                   unsigned short* __restrict__ src_sorted,
                   _Float16* __restrict__ node_mean) {
    __shared__ int cnt[BSIZE];
    __shared__ int sloc[BSIZE + 1];
    __shared__ int cur[BSIZE];
    __shared__ unsigned short perm[WCAP];

    int tid = threadIdx.x;
    int b = blockIdx.x;
    int wlo = bucket_off[b], whi = bucket_off[b + 1];
    int n_e = whi - wlo;

    if (tid < BSIZE) cnt[tid] = 0;
    __syncthreads();
    for (int i = tid; i < n_e; i += 512)
        atomicAdd(&cnt[coarseE[wlo + i] >> 16], 1);
    __syncthreads();
    if (tid == 0) {
        int run = 0;
        #pragma unroll
        for (int k = 0; k < BSIZE; ++k) { sloc[k] = run; run += cnt[k]; }
        sloc[BSIZE] = run;
    }
    __syncthreads();
    int nbase = b << BSH;
    if (tid < BSIZE) {
        cur[tid] = sloc[tid];
        if (nbase + tid < N_NODES) row_off[nbase + tid] = wlo + sloc[tid];
    }
    if (b == NB - 1 && tid == 0) row_off[N_NODES] = N_EDGES;
    __syncthreads();
    for (int i = tid; i < n_e; i += 512) {
        int id = coarseE[wlo + i];
        int l = id >> 16;
        int p = atomicAdd(&cur[l], 1);
        if (p < WCAP) perm[p] = (unsigned short)i;
        src_sorted[wlo + p] = (unsigned short)(id & 0xFFFF);
    }
    __syncthreads();

    // reduce: 8 waves x 8 nodes each; lane = eslot*8 + q, 8 edges/iter
    int wv = tid >> 6, lane = tid & 63, eslot = lane >> 3, q = lane & 7;
    for (int k = 0; k < 8; ++k) {
        int n = wv * 8 + k;
        if (nbase + n >= N_NODES) break;
        int a0 = sloc[n], a1 = sloc[n + 1];
        f4 acc = {0.f, 0.f, 0.f, 0.f};
        for (int i = a0 + eslot; i < a1; i += 8) {
            int widx = perm[i];
            h4 v = *reinterpret_cast<const h4*>(
                &coarseR[((size_t)(wlo + widx) << 5) + q * 4]);
            acc += __builtin_convertvector(v, f4);
        }
        #pragma unroll
        for (int m = 8; m <= 32; m <<= 1) {
            acc.x += __shfl_xor(acc.x, m);
            acc.y += __shfl_xor(acc.y, m);
            acc.z += __shfl_xor(acc.z, m);
            acc.w += __shfl_xor(acc.w, m);
        }
        if (eslot == 0) {
            float r = 1.0f / fmaxf((float)(a1 - a0), 1.0f);
            f4 o = acc * r;
            *reinterpret_cast<h4*>(&node_mean[(size_t)(nbase + n) * F + q * 4]) =
                __builtin_convertvector(o, h4);
        }
    }
}

// ---------- stage 3 + projection fused: node_p(f16) = (sum mean[src]) @ W^T ----------
__global__ __launch_bounds__(256)
void k_node_h_project(const unsigned short* __restrict__ src_sorted,
                      const int* __restrict__ row_off,
                      const _Float16* __restrict__ node_mean,
                      const float* __restrict__ W,
                      _Float16* __restrict__ node_p) {
    __shared__ float Wl[32][33];
    __shared__ float hr[4][36];

    int tid = threadIdx.x;
    #pragma unroll
    for (int i = tid; i < 1024; i += 256) Wl[i >> 5][i & 31] = W[i];

    int wv    = tid >> 6;        // wave 0..3 = local node
    int lane  = tid & 63;
    int eslot = lane >> 3;
    int q     = lane & 7;
    int n     = blockIdx.x * 4 + wv;     // N_NODES = 12500*4, no tail

    int s0 = row_off[n];
    int s1 = row_off[n + 1];

    f4 acc = {0.f, 0.f, 0.f, 0.f};
    int i = s0 + eslot;
    int s = (i < s1) ? (int)src_sorted[i] : 0;
    while (i < s1) {
        int inext = i + 8;
        int snext = (inext < s1) ? (int)src_sorted[inext] : 0;
        h4 v = *reinterpret_cast<const h4*>(&node_mean[(size_t)s * F + q * 4]);
        acc += __builtin_convertvector(v, f4);
        i = inext; s = snext;
    }
    #pragma unroll
    for (int m = 8; m <= 32; m <<= 1) {
        acc.x += __shfl_xor(acc.x, m);
        acc.y += __shfl_xor(acc.y, m);
        acc.z += __shfl_xor(acc.z, m);
        acc.w += __shfl_xor(acc.w, m);
    }
    if (eslot == 0) {
        *reinterpret_cast<f4*>(&hr[wv][q * 4]) = acc;
    }
    __syncthreads();

    if (tid < 128) {
        int ln = tid >> 5;
        int o  = tid & 31;
        float sacc = 0.f;
        #pragma unroll
        for (int i2 = 0; i2 < 32; ++i2) sacc += hr[ln][i2] * Wl[o][i2];
        node_p[(size_t)(blockIdx.x * 4 + ln) * F + o] = (_Float16)sacc;
    }
}

// ---------- stage 4: out[e] = 0.5*(node_p[src] + node_p[dst]) + b ----------
__global__ __launch_bounds__(256)
void k_edge_out(const int* __restrict__ src,
                const int* __restrict__ dst,
                const _Float16* __restrict__ node_p,
                const float* __restrict__ b,
                float* __restrict__ out) {
    int tid = blockIdx.x * blockDim.x + threadIdx.x;   // e*8 + q
    if (tid >= N_EDGES * 8) return;
    int e = tid >> 3;
    int q = tid & 7;
    int s = nt_loadi(&src[e]);
    int d = nt_loadi(&dst[e]);

    h4 ah = *reinterpret_cast<const h4*>(&node_p[(size_t)s * F + q * 4]);
    h4 ch = *reinterpret_cast<const h4*>(&node_p[(size_t)d * F + q * 4]);
    const f4 a  = __builtin_convertvector(ah, f4);
    const f4 c  = __builtin_convertvector(ch, f4);
    const f4 bb = *reinterpret_cast<const f4*>(&b[q * 4]);

    f4 r = 0.5f * (a + c) + bb;
    __builtin_nontemporal_store(r, (f4*)&out[(size_t)e * F + q * 4]);
}

extern "C" void kernel_launch(void* const* d_in, const int* in_sizes, int n_in,
                              void* d_out, int out_size, void* d_ws, size_t ws_size,
                              hipStream_t stream) {
    const float* inputs = (const float*)d_in[0];
    const int*   src    = (const int*)d_in[1];
    const int*   dst    = (const int*)d_in[2];
    const float* W      = (const float*)d_in[3];
    const float* b      = (const float*)d_in[4];
    float* out = (float*)d_out;

    // Workspace layout: ints first, then 16B-aligned f16 arrays, then ushorts.
    int*  coarseE    = (int*)d_ws;                         // E
    int*  bhist      = coarseE + N_EDGES;                  // NB
    int*  bucket_off = bhist + NB;                         // NB+1
    int*  cursor     = bucket_off + NB + 1;                // NB
    int*  row_off    = cursor + NB;                        // N+1
    size_t ihead = (size_t)N_EDGES + 3 * NB + 1 + N_NODES + 1;
    ihead = (ihead + 3) & ~(size_t)3;                      // 16B align
    _Float16* coarseR   = (_Float16*)((int*)d_ws + ihead); // E*F
    _Float16* node_mean = coarseR + (size_t)N_EDGES * F;   // N*F
    _Float16* node_p    = node_mean + (size_t)N_NODES * F; // N*F
    unsigned short* src_sorted =
        (unsigned short*)(node_p + (size_t)N_NODES * F);   // E

    hipMemsetAsync(bhist, 0, NB * sizeof(int), stream);

    k_bhist<<<512, 256, 0, stream>>>(dst, bhist);
    k_bscan<<<1, 1024, 0, stream>>>(bhist, bucket_off, cursor);
    k_coarse_rows<<<NCHUNK, 256, 0, stream>>>(
        dst, src, inputs, cursor, coarseE, coarseR);
    k_bucket_mean<<<NB, 512, 0, stream>>>(
        coarseE, bucket_off, coarseR, row_off, src_sorted, node_mean);
    k_node_h_project<<<N_NODES / 4, 256, 0, stream>>>(
        src_sorted, row_off, node_mean, W, node_p);
    k_edge_out<<<(N_EDGES * 8 + 255) / 256, 256, 0, stream>>>(src, dst, node_p, b, out);
}

// Round 10
// 218.574 us; speedup vs baseline: 1.3216x; 1.3216x over previous
//
#include <hip/hip_runtime.h>

#define N_NODES 50000
#define N_EDGES 1600000
#define F 32
#define BSH 7                               // 128 nodes per bucket
#define BSIZE (1 << BSH)
#define NB ((N_NODES + BSIZE - 1) >> BSH)   // 391 buckets
#define FILL_CHUNK 6144                     // 261 blocks; runs ~15.7 entries
#define EMASK 0x1FFFFF

typedef float f4 __attribute__((ext_vector_type(4)));
typedef _Float16 h4 __attribute__((ext_vector_type(4)));

__device__ __forceinline__ f4 nt_load4(const float* p) {
    return __builtin_nontemporal_load((const f4*)p);
}
__device__ __forceinline__ int nt_loadi(const int* p) {
    return __builtin_nontemporal_load(p);
}
__device__ __forceinline__ unsigned short nt_loadu16(const unsigned short* p) {
    return __builtin_nontemporal_load(p);
}

// ---------- coarse bucket histogram (LDS-privatized) ----------
__global__ __launch_bounds__(256)
void k_bhist(const int* __restrict__ dst, int* __restrict__ bhist) {
    __shared__ int lh[NB];
    for (int i = threadIdx.x; i < NB; i += 256) lh[i] = 0;
    __syncthreads();
    for (int e = blockIdx.x * blockDim.x + threadIdx.x; e < N_EDGES;
         e += gridDim.x * blockDim.x)
        atomicAdd(&lh[dst[e] >> BSH], 1);
    __syncthreads();
    for (int i = threadIdx.x; i < NB; i += 256)
        if (lh[i]) atomicAdd(&bhist[i], lh[i]);
}

// ---------- scan 391 bucket counts -> offsets + fill cursors ----------
__global__ __launch_bounds__(512)
void k_bscan(const int* __restrict__ bhist,
             int* __restrict__ bucket_off,
             int* __restrict__ cursor) {
    __shared__ int s[512];
    int t = threadIdx.x;
    int v = (t < NB) ? bhist[t] : 0;
    s[t] = v;
    __syncthreads();
    for (int off = 1; off < 512; off <<= 1) {
        int u = (t >= off) ? s[t - off] : 0;
        __syncthreads();
        s[t] += u;
        __syncthreads();
    }
    if (t < NB) {
        int ex = s[t] - v;
        bucket_off[t] = ex;
        cursor[t] = ex;
    }
    if (t == NB - 1) bucket_off[NB] = s[t];
}

// ---------- phase A: bin edges into bucket runs; one global read of dst/src ----------
__global__ __launch_bounds__(256)
void k_coarse_fill(const int* __restrict__ dst,
                   const int* __restrict__ src,
                   int* __restrict__ cursor,
                   int* __restrict__ coarseE,
                   unsigned short* __restrict__ coarseS) {
    __shared__ int lh[NB];
    __shared__ int gb[NB];
    __shared__ unsigned int ds[FILL_CHUNK];   // d<<16 | src, staged coalesced
    int lo = blockIdx.x * FILL_CHUNK;
    int hi = min(lo + FILL_CHUNK, N_EDGES);
    int n_e = hi - lo;

    for (int i = threadIdx.x; i < NB; i += 256) lh[i] = 0;
    __syncthreads();
    for (int i = threadIdx.x; i < n_e; i += 256) {
        int d = dst[lo + i];
        ds[i] = ((unsigned)d << 16) | (unsigned)src[lo + i];
        atomicAdd(&lh[d >> BSH], 1);
    }
    __syncthreads();
    for (int i = threadIdx.x; i < NB; i += 256) {
        gb[i] = atomicAdd(&cursor[i], lh[i]);
        lh[i] = 0;                  // reuse as rank counter
    }
    __syncthreads();
    for (int i = threadIdx.x; i < n_e; i += 256) {
        unsigned v = ds[i];
        int d = (int)(v >> 16);
        int bk = d >> BSH;
        int r = atomicAdd(&lh[bk], 1);
        int p = gb[bk] + r;
        coarseE[p] = (lo + i) | ((d & (BSIZE - 1)) << 21);   // e < 2^21
        coarseS[p] = (unsigned short)(v & 0xFFFFu);
    }
}

// ---------- phase B: exact CSR within each 128-node bucket ----------
__global__ __launch_bounds__(256)
void k_exact_fill(const int* __restrict__ coarseE,
                  const unsigned short* __restrict__ coarseS,
                  const int* __restrict__ bucket_off,
                  int* __restrict__ row_off,
                  int* __restrict__ eid_sorted,
                  unsigned short* __restrict__ src_sorted) {
    __shared__ int cnt[BSIZE];
    __shared__ int s[BSIZE];
    __shared__ int cur[BSIZE];
    int tid = threadIdx.x;
    int b = blockIdx.x;
    int lo = bucket_off[b], hi = bucket_off[b + 1];

    if (tid < BSIZE) cnt[tid] = 0;
    __syncthreads();
    for (int i = lo + tid; i < hi; i += 256)
        atomicAdd(&cnt[(nt_loadi(&coarseE[i]) >> 21) & (BSIZE - 1)], 1);
    __syncthreads();
    if (tid < BSIZE) s[tid] = cnt[tid];
    __syncthreads();
    for (int off = 1; off < BSIZE; off <<= 1) {
        int v = 0;
        if (tid < BSIZE && tid >= off) v = s[tid - off];
        __syncthreads();
        if (tid < BSIZE) s[tid] += v;
        __syncthreads();
    }
    int nbase = b << BSH;
    if (tid < BSIZE) {
        int base = lo + s[tid] - cnt[tid];   // exclusive scan + bucket base
        cur[tid] = base;
        if (nbase + tid < N_NODES) row_off[nbase + tid] = base;
    }
    if (b == NB - 1 && tid == 0) row_off[N_NODES] = N_EDGES;
    __syncthreads();
    for (int i = lo + tid; i < hi; i += 256) {
        int ev = nt_loadi(&coarseE[i]);
        int l = (ev >> 21) & (BSIZE - 1);
        int p = atomicAdd(&cur[l], 1);
        eid_sorted[p] = ev & EMASK;
        src_sorted[p] = nt_loadu16(&coarseS[i]);
    }
}

// ---------- stage 1+2: node_mean (f16 out) via per-node wave reduce ----------
__global__ __launch_bounds__(256)
void k_node_mean(const float* __restrict__ inputs,
                 const int* __restrict__ eid_sorted,
                 const int* __restrict__ row_off,
                 _Float16* __restrict__ node_mean) {
    int wave = (blockIdx.x * blockDim.x + threadIdx.x) >> 6;
    if (wave >= N_NODES) return;
    int lane  = threadIdx.x & 63;
    int eslot = lane >> 3;       // 0..7
    int q     = lane & 7;        // float4 quad

    int s0 = row_off[wave];
    int s1 = row_off[wave + 1];

    f4 acc = {0.f, 0.f, 0.f, 0.f};
    int i = s0 + eslot;
    int e = (i < s1) ? eid_sorted[i] : 0;
    while (i < s1) {
        int inext = i + 8;
        int enext = (inext < s1) ? eid_sorted[inext] : 0;   // prefetch next eid
        f4 v = nt_load4(&inputs[(size_t)e * F + q * 4]);    // NT: zero reuse
        acc += v;
        i = inext; e = enext;
    }
    #pragma unroll
    for (int m = 8; m <= 32; m <<= 1) {
        acc.x += __shfl_xor(acc.x, m);
        acc.y += __shfl_xor(acc.y, m);
        acc.z += __shfl_xor(acc.z, m);
        acc.w += __shfl_xor(acc.w, m);
    }
    if (eslot == 0) {
        float r = 1.0f / fmaxf((float)(s1 - s0), 1.0f);
        f4 o = acc * r;
        *reinterpret_cast<h4*>(&node_mean[(size_t)wave * F + q * 4]) =
            __builtin_convertvector(o, h4);
    }
}

// ---------- stage 3 + projection fused: node_p(f16) = (sum mean[src]) @ W^T ----------
__global__ __launch_bounds__(256)
void k_node_h_project(const unsigned short* __restrict__ src_sorted,
                      const int* __restrict__ row_off,
                      const _Float16* __restrict__ node_mean,
                      const float* __restrict__ W,
                      _Float16* __restrict__ node_p) {
    __shared__ float Wl[32][33];
    __shared__ float hr[4][36];   // stride 36: float4-aligned rows

    int tid = threadIdx.x;
    #pragma unroll
    for (int i = tid; i < 1024; i += 256) Wl[i >> 5][i & 31] = W[i];

    int wv    = tid >> 6;        // wave 0..3 = local node
    int lane  = tid & 63;
    int eslot = lane >> 3;
    int q     = lane & 7;
    int n     = blockIdx.x * 4 + wv;     // N_NODES = 12500*4, no tail

    int s0 = row_off[n];
    int s1 = row_off[n + 1];

    f4 acc = {0.f, 0.f, 0.f, 0.f};
    int i = s0 + eslot;
    int s = (i < s1) ? (int)src_sorted[i] : 0;
    while (i < s1) {
        int inext = i + 8;
        int snext = (inext < s1) ? (int)src_sorted[inext] : 0;
        h4 v = *reinterpret_cast<const h4*>(&node_mean[(size_t)s * F + q * 4]);
        acc += __builtin_convertvector(v, f4);
        i = inext; s = snext;
    }
    #pragma unroll
    for (int m = 8; m <= 32; m <<= 1) {
        acc.x += __shfl_xor(acc.x, m);
        acc.y += __shfl_xor(acc.y, m);
        acc.z += __shfl_xor(acc.z, m);
        acc.w += __shfl_xor(acc.w, m);
    }
    if (eslot == 0) {
        *reinterpret_cast<f4*>(&hr[wv][q * 4]) = acc;
    }
    __syncthreads();

    if (tid < 128) {
        int ln = tid >> 5;       // local node
        int o  = tid & 31;       // output channel
        float sacc = 0.f;
        #pragma unroll
        for (int i2 = 0; i2 < 32; ++i2) sacc += hr[ln][i2] * Wl[o][i2];
        node_p[(size_t)(blockIdx.x * 4 + ln) * F + o] = (_Float16)sacc;
    }
}

// ---------- stage 4: out[e] = 0.5*(node_p[src] + node_p[dst]) + b ----------
__global__ __launch_bounds__(256)
void k_edge_out(const int* __restrict__ src,
                const int* __restrict__ dst,
                const _Float16* __restrict__ node_p,
                const float* __restrict__ b,
                float* __restrict__ out) {
    int tid = blockIdx.x * blockDim.x + threadIdx.x;   // e*8 + q
    if (tid >= N_EDGES * 8) return;
    int e = tid >> 3;
    int q = tid & 7;
    int s = nt_loadi(&src[e]);     // streamed once: keep out of L2
    int d = nt_loadi(&dst[e]);

    h4 ah = *reinterpret_cast<const h4*>(&node_p[(size_t)s * F + q * 4]);
    h4 ch = *reinterpret_cast<const h4*>(&node_p[(size_t)d * F + q * 4]);
    const f4 a  = __builtin_convertvector(ah, f4);
    const f4 c  = __builtin_convertvector(ch, f4);
    const f4 bb = *reinterpret_cast<const f4*>(&b[q * 4]);

    f4 r = 0.5f * (a + c) + bb;
    __builtin_nontemporal_store(r, (f4*)&out[(size_t)e * F + q * 4]);
}

extern "C" void kernel_launch(void* const* d_in, const int* in_sizes, int n_in,
                              void* d_out, int out_size, void* d_ws, size_t ws_size,
                              hipStream_t stream) {
    const float* inputs = (const float*)d_in[0];
    const int*   src    = (const int*)d_in[1];
    const int*   dst    = (const int*)d_in[2];
    const float* W      = (const float*)d_in[3];
    const float* b      = (const float*)d_in[4];
    float* out = (float*)d_out;

    // Workspace layout: 4B-aligned ints first, f16/ushort (2B) last.
    int*  coarseE    = (int*)d_ws;                         // E
    int*  eid_sorted = coarseE + N_EDGES;                  // E
    int*  bhist      = eid_sorted + N_EDGES;               // NB
    int*  bucket_off = bhist + NB;                         // NB+1
    int*  cursor     = bucket_off + NB + 1;                // NB
    int*  row_off    = cursor + NB;                        // N+1
    _Float16* node_mean = (_Float16*)(row_off + N_NODES + 1);       // N*F
    _Float16* node_p    = node_mean + (size_t)N_NODES * F;          // N*F
    unsigned short* coarseS    = (unsigned short*)(node_p + (size_t)N_NODES * F); // E
    unsigned short* src_sorted = coarseS + N_EDGES;        // E

    hipMemsetAsync(bhist, 0, NB * sizeof(int), stream);

    k_bhist<<<512, 256, 0, stream>>>(dst, bhist);
    k_bscan<<<1, 512, 0, stream>>>(bhist, bucket_off, cursor);
    k_coarse_fill<<<(N_EDGES + FILL_CHUNK - 1) / FILL_CHUNK, 256, 0, stream>>>(
        dst, src, cursor, coarseE, coarseS);
    k_exact_fill<<<NB, 256, 0, stream>>>(
        coarseE, coarseS, bucket_off, row_off, eid_sorted, src_sorted);

    int node_blocks = (N_NODES + 3) / 4;   // 1 wave per node, 4 waves/block
    k_node_mean<<<node_blocks, 256, 0, stream>>>(inputs, eid_sorted, row_off, node_mean);
    k_node_h_project<<<N_NODES / 4, 256, 0, stream>>>(
        src_sorted, row_off, node_mean, W, node_p);
    k_edge_out<<<(N_EDGES * 8 + 255) / 256, 256, 0, stream>>>(src, dst, node_p, b, out);
}